// Round 10
// baseline (68.882 us; speedup 1.0000x reference)
//
#include <hip/hip_runtime.h>
#include <hip/hip_bf16.h>

#define NN 1024   // batch
#define ND 512    // embed dim (K)
#define NM 512    // prototypes

typedef __attribute__((ext_vector_type(8))) short short8;   // 8 bf16 = 4 VGPR (MFMA A/B frag)
typedef __attribute__((ext_vector_type(4))) float f32x4;    // MFMA C/D frag

__device__ __forceinline__ ushort f2bf(float f) {
    __hip_bfloat16 h = __float2bfloat16(f);          // HW cvt (RNE), compiler pairs to cvt_pk
    union { __hip_bfloat16 h; ushort u; } c; c.h = h;
    return c.u;
}

// ---------------------------------------------------------------------------
// out[n,m] = -0.5*sqrt(xx[n] + pp[m] - 2*dot(x_n, p_m))
// LDS-free, barrier-free main loop: one wave owns one 16x16 output tile
// (split-K x2), fragments loaded DIRECTLY from global per-lane:
//   A-frag: lane(fr,fq) reads 8 k-contiguous f32 of X row tn*16+fr  (2xfloat4)
//   B-frag: lane(fr,fq) reads 8 stride-NM f32 of P col tm*16+fr     (8 dwords,
//           16 lanes/quadrant cover 64B contiguous -> L2-friendly)
// In-register f32->bf16 convert; norms folded from the same registers and
// reduced with 2x shfl_xor (lanes {l, l^16, l^32, l^48} share fr).
// No per-step barriers -> no vmcnt(0) drains; waves overlap freely (m114).
// Split-K x2: serial chain 8 steps; 1024 blocks x 4 waves = 16 waves/CU.
// One barrier total for the split-K combine (3KB LDS).
// ---------------------------------------------------------------------------
__global__ __launch_bounds__(256, 4) void fused_kernel(const float* __restrict__ X,
                                                       const float* __restrict__ P,
                                                       float* __restrict__ out) {
    __shared__ float red[2][64][8];   // [tile][lane][acc0..3, xr, pr] (+pad)

    const int t    = threadIdx.x;
    const int lane = t & 63;
    const int wid  = t >> 6;          // 0..3
    const int kh   = wid & 1;         // K-half (0: k<256, 1: k>=256)
    const int tl   = wid >> 1;        // tile slot within block (0..1)
    const int T    = blockIdx.x * 2 + tl;     // 0..2047
    const int tn   = T >> 5;          // 0..63  (16-row n-tile)
    const int tm   = T & 31;          // 0..31  (16-col m-tile)
    const int fr   = lane & 15, fq = lane >> 4;

    const float* ap = X + (tn * 16 + fr) * ND + kh * 256 + fq * 8;
    const float* bp = P + (kh * 256 + fq * 8) * NM + tm * 16 + fr;

    float xacc = 0.f, pacc = 0.f;
    f32x4 acc = {0.f, 0.f, 0.f, 0.f};

    float4 a0[2], a1[2];
    float  b[2][8];

    // prologue (step 0)
    a0[0] = *(const float4*)ap;
    a1[0] = *(const float4*)(ap + 4);
    #pragma unroll
    for (int j = 0; j < 8; ++j) b[0][j] = bp[j * NM];

    #pragma unroll
    for (int s = 0; s < 8; ++s) {
        const int cur = s & 1, nxt = cur ^ 1;   // static after unroll

        // prefetch next step (no barrier anywhere -> stays in flight over MFMA)
        if (s < 7) {
            const float* pa = ap + (s + 1) * 32;
            a0[nxt] = *(const float4*)pa;
            a1[nxt] = *(const float4*)(pa + 4);
            const float* pb = bp + (s + 1) * 32 * NM;
            #pragma unroll
            for (int j = 0; j < 8; ++j) b[nxt][j] = pb[j * NM];
        }

        // norms + convert current
        union { short8 v; ushort u[8]; } af, bf;
        {
            float4 v0 = a0[cur], v1 = a1[cur];
            xacc = fmaf(v0.x, v0.x, xacc); xacc = fmaf(v0.y, v0.y, xacc);
            xacc = fmaf(v0.z, v0.z, xacc); xacc = fmaf(v0.w, v0.w, xacc);
            xacc = fmaf(v1.x, v1.x, xacc); xacc = fmaf(v1.y, v1.y, xacc);
            xacc = fmaf(v1.z, v1.z, xacc); xacc = fmaf(v1.w, v1.w, xacc);
            af.u[0] = f2bf(v0.x); af.u[1] = f2bf(v0.y);
            af.u[2] = f2bf(v0.z); af.u[3] = f2bf(v0.w);
            af.u[4] = f2bf(v1.x); af.u[5] = f2bf(v1.y);
            af.u[6] = f2bf(v1.z); af.u[7] = f2bf(v1.w);
            #pragma unroll
            for (int j = 0; j < 8; ++j) {
                float bv = b[cur][j];
                pacc = fmaf(bv, bv, pacc);
                bf.u[j] = f2bf(bv);
            }
        }
        acc = __builtin_amdgcn_mfma_f32_16x16x32_bf16(af.v, bf.v, acc, 0, 0, 0);
    }

    // reduce norms over fq (lanes l, l^16, l^32, l^48 share fr)
    xacc += __shfl_xor(xacc, 16, 64); xacc += __shfl_xor(xacc, 32, 64);
    pacc += __shfl_xor(pacc, 16, 64); pacc += __shfl_xor(pacc, 32, 64);

    // split-K combine: kh==1 publishes, kh==0 adds and writes out
    if (kh == 1) {
        #pragma unroll
        for (int r = 0; r < 4; ++r) red[tl][lane][r] = acc[r];
        red[tl][lane][4] = xacc;
        red[tl][lane][5] = pacc;
    }
    __syncthreads();
    if (kh == 0) {
        #pragma unroll
        for (int r = 0; r < 4; ++r) acc[r] += red[tl][lane][r];
        xacc += red[tl][lane][4];
        pacc += red[tl][lane][5];

        // epilogue: C/D layout col=lane&15, row=(lane>>4)*4+reg  [m89/m91]
        // pp[col=fr] is this lane's pacc; xx[row] fetched by lane shuffle.
        float* orow = out + (tn * 16) * NM + tm * 16 + fr;
        #pragma unroll
        for (int r = 0; r < 4; ++r) {
            const int rowl = fq * 4 + r;
            const float xv = __shfl(xacc, rowl, 64);
            orow[rowl * NM] = -0.5f * sqrtf(fmaxf(xv + pacc - 2.f * acc[r], 0.f));
        }
    }
}

extern "C" void kernel_launch(void* const* d_in, const int* in_sizes, int n_in,
                              void* d_out, int out_size, void* d_ws, size_t ws_size,
                              hipStream_t stream) {
    const float* x     = (const float*)d_in[0];   // (N, D) f32
    const float* proto = (const float*)d_in[1];   // (D, M) f32
    float* out = (float*)d_out;                   // (N, M) f32
    hipLaunchKernelGGL(fused_kernel, dim3(1024), dim3(256), 0, stream,
                       x, proto, out);
}

// Round 11
// 67.885 us; speedup vs baseline: 1.0147x; 1.0147x over previous
//
#include <hip/hip_runtime.h>
#include <hip/hip_bf16.h>

#define NN 1024   // batch
#define ND 512    // embed dim (K)
#define NM 512    // prototypes

typedef __attribute__((ext_vector_type(8))) short short8;   // 8 bf16 = 4 VGPR (MFMA A/B frag)
typedef __attribute__((ext_vector_type(4))) float f32x4;    // MFMA C/D frag

__device__ __forceinline__ ushort f2bf(float f) {           // f32 -> bf16 RNE
    union { float f; unsigned u; } v; v.f = f;
    unsigned r = v.u + 0x7FFFu + ((v.u >> 16) & 1u);
    return (ushort)(r >> 16);
}

// ---------------------------------------------------------------------------
// prep: one pass over inputs, done ONCE (not per-tile):
//   bid <  256: X (f32, k-contig) -> Xb (bf16), fold row norms xx[n]
//   bid >= 256: P (k,m) --LDS transpose--> Pt (m,k) bf16, fold 64-k partial
//               column norms into pp_part[ktile][m]   (no atomics)
// ---------------------------------------------------------------------------
__global__ __launch_bounds__(256) void prep_kernel(const float* __restrict__ X,
                                                   const float* __restrict__ P,
                                                   ushort* __restrict__ Xb,
                                                   ushort* __restrict__ Pt,
                                                   float* __restrict__ xx,
                                                   float* __restrict__ ppp) {
    const int bid = blockIdx.x, t = threadIdx.x;
    if (bid < 256) {
        const int wid = t >> 6, lane = t & 63;
        const int row = bid * 4 + wid;
        const float* src = X + row * ND + lane * 8;
        float4 v0 = *(const float4*)src, v1 = *(const float4*)(src + 4);
        float s = 0.f;
        s = fmaf(v0.x, v0.x, s); s = fmaf(v0.y, v0.y, s);
        s = fmaf(v0.z, v0.z, s); s = fmaf(v0.w, v0.w, s);
        s = fmaf(v1.x, v1.x, s); s = fmaf(v1.y, v1.y, s);
        s = fmaf(v1.z, v1.z, s); s = fmaf(v1.w, v1.w, s);
        unsigned w0 = (unsigned)f2bf(v0.x) | ((unsigned)f2bf(v0.y) << 16);
        unsigned w1 = (unsigned)f2bf(v0.z) | ((unsigned)f2bf(v0.w) << 16);
        unsigned w2 = (unsigned)f2bf(v1.x) | ((unsigned)f2bf(v1.y) << 16);
        unsigned w3 = (unsigned)f2bf(v1.z) | ((unsigned)f2bf(v1.w) << 16);
        *(uint4*)&Xb[row * ND + lane * 8] = make_uint4(w0, w1, w2, w3);
        #pragma unroll
        for (int off = 32; off > 0; off >>= 1) s += __shfl_xor(s, off, 64);
        if (lane == 0) xx[row] = s;
    } else {
        __shared__ float Ls[64][65];             // +1 pad: conflict-free columns
        const int b  = bid - 256;
        const int m0 = (b & 7) * 64;
        const int k0 = (b >> 3) * 64;
        {
            const int r = t >> 2, q = t & 3;
            const float* src = P + (k0 + r) * NM + m0 + q * 4;
            #pragma unroll
            for (int j = 0; j < 4; ++j)
                *(float4*)&Ls[r][q * 4 + j * 16] = *(const float4*)(src + j * 16);
        }
        __syncthreads();
        {
            const int m = t >> 2, kq = (t & 3) * 16;  // 16 k of one m-row
            float pacc = 0.f;
            unsigned w[8];
            #pragma unroll
            for (int i = 0; i < 8; ++i) {
                float lo = Ls[kq + 2 * i][m], hi = Ls[kq + 2 * i + 1][m];
                pacc = fmaf(lo, lo, pacc); pacc = fmaf(hi, hi, pacc);
                w[i] = (unsigned)f2bf(lo) | ((unsigned)f2bf(hi) << 16);
            }
            ushort* dst = Pt + (m0 + m) * ND + k0 + kq;
            *(uint4*)(dst)     = make_uint4(w[0], w[1], w[2], w[3]);
            *(uint4*)(dst + 8) = make_uint4(w[4], w[5], w[6], w[7]);
            pacc += __shfl_down(pacc, 2, 4);
            pacc += __shfl_down(pacc, 1, 4);
            if ((t & 3) == 0) ppp[(b >> 3) * NM + m0 + m] = pacc;
        }
    }
}

// ---------------------------------------------------------------------------
// gemm: out[n,m] = -0.5*sqrt(xx[n] + pp[m] - 2*dot(x_n, p_m))
// Wave = one 16x16 tile. Per K-step: ONE b128 global load per operand
// (16B k-contiguous frag from Xb/Pt, offset-immediate addressable) + one
// mfma_f32_16x16x32_bf16. No LDS, no barriers, no staging VALU in the loop;
// depth-2 register pipeline. 2048 waves = 512 blocks (2 waves/SIMD).
// T-map: tn = T&63 fastest -> per XCD: 128 Xb rows (256KB) + full Pt;
// 4 waves/block share identical Pt rows (L1 hits).
// ---------------------------------------------------------------------------
__global__ __launch_bounds__(256, 2) void gemm_kernel(const ushort* __restrict__ Xb,
                                                      const ushort* __restrict__ Pt,
                                                      const float* __restrict__ xx,
                                                      const float* __restrict__ ppp,
                                                      float* __restrict__ out) {
    const int t    = threadIdx.x;
    const int lane = t & 63;
    const int wid  = t >> 6;
    const int T    = blockIdx.x * 4 + wid;
    const int tn   = T & 63;          // 0..63 (fastest -> XCD locality on Xb)
    const int tm   = T >> 6;          // 0..31
    const int fr   = lane & 15, fq = lane >> 4;

    const ushort* ap = Xb + (tn * 16 + fr) * ND + fq * 8;
    const ushort* bp = Pt + (tm * 16 + fr) * ND + fq * 8;

    f32x4 acc = {0.f, 0.f, 0.f, 0.f};
    short8 a[2], b[2];
    a[0] = *(const short8*)ap;
    b[0] = *(const short8*)bp;

    #pragma unroll
    for (int s = 0; s < 16; ++s) {
        const int cur = s & 1, nxt = cur ^ 1;   // static after unroll
        if (s < 15) {
            a[nxt] = *(const short8*)(ap + (s + 1) * 32);
            b[nxt] = *(const short8*)(bp + (s + 1) * 32);
        }
        acc = __builtin_amdgcn_mfma_f32_16x16x32_bf16(a[cur], b[cur], acc, 0, 0, 0);
    }

    // epilogue: C/D layout col=lane&15, row=(lane>>4)*4+reg  [m89/m91]
    float4 xv = *(const float4*)(xx + tn * 16 + fq * 4);
    float pv = 0.f;
    #pragma unroll
    for (int i = 0; i < 8; ++i) pv += ppp[i * NM + tm * 16 + fr];
    float xvv[4] = {xv.x, xv.y, xv.z, xv.w};
    float* orow = out + (tn * 16) * NM + tm * 16 + fr;
    #pragma unroll
    for (int r = 0; r < 4; ++r)
        orow[(fq * 4 + r) * NM] = -0.5f * sqrtf(fmaxf(xvv[r] + pv - 2.f * acc[r], 0.f));
}

extern "C" void kernel_launch(void* const* d_in, const int* in_sizes, int n_in,
                              void* d_out, int out_size, void* d_ws, size_t ws_size,
                              hipStream_t stream) {
    const float* x     = (const float*)d_in[0];   // (N, D) f32
    const float* proto = (const float*)d_in[1];   // (D, M) f32
    float* out = (float*)d_out;                   // (N, M) f32

    char* w = (char*)d_ws;
    ushort* Xb  = (ushort*)w;                         // 1 MB
    ushort* Pt  = (ushort*)(w + (1u << 20));          // 512 KB
    float*  xx  = (float*)(w + (1u << 20) + (1u << 19));   // 4 KB
    float*  ppp = xx + NN;                            // 8*512 f32 = 16 KB

    hipLaunchKernelGGL(prep_kernel, dim3(256 + 64), dim3(256), 0, stream,
                       x, proto, Xb, Pt, xx, ppp);
    hipLaunchKernelGGL(gemm_kernel, dim3(512), dim3(256), 0, stream,
                       Xb, Pt, xx, ppp, out);
}

// Round 12
// 62.665 us; speedup vs baseline: 1.0992x; 1.0833x over previous
//
#include <hip/hip_runtime.h>
#include <hip/hip_bf16.h>

#define NN 1024   // batch
#define ND 512    // embed dim (K)
#define NM 512    // prototypes

typedef __attribute__((ext_vector_type(8))) short short8;   // 8 bf16 = 4 VGPR (MFMA A/B frag)
typedef __attribute__((ext_vector_type(4))) float f32x4;    // MFMA C/D frag

__device__ __forceinline__ ushort f2bf(float f) {           // f32 -> bf16 RNE
    union { float f; unsigned u; } v; v.f = f;
    unsigned r = v.u + 0x7FFFu + ((v.u >> 16) & 1u);
    return (ushort)(r >> 16);
}

// ---------------------------------------------------------------------------
// CHAMPION (benched 62.05 us, Round 8).
// out[n,m] = -0.5*sqrt(xx[n] + pp[m] - 2*dot(x_n, p_m))
// 32n x 64m tile, 256 blocks, 512 threads (8 waves, 2/SIMD), BK=64,
// mfma_f32_16x16x32_bf16, one 16x16 frag per wave (2x4 wave grid).
// P transposed in-flight (coalesced along m); norms fused into staging.
// Early prefetch + reg dbuf. Grid (n-tiles, m-tiles): XCD = linear%8 = x%8
// -> each XCD reuses 4 X-slabs + full P (~1.25MB working set < 4MB L2).
// Measured environment floor: every replay follows a 256MB ws-poison fill
// (40.4us, evicts L2+L3, parks DVFS); kernel wall ~20us is set by that
// environment, not structure (5 diverse structures: 20-27us).
// ---------------------------------------------------------------------------
__global__ __launch_bounds__(512) void fused_kernel(const float* __restrict__ X,
                                                    const float* __restrict__ P,
                                                    float* __restrict__ out) {
    // 72-elem rows (144B): 16B-aligned chunks, >=2-way-only bank aliasing (free)
    __shared__ ushort As[2][32][72];
    __shared__ ushort Bs[2][64][72];
    __shared__ float  xx_s[32];
    __shared__ float  pp_part[8][64];

    const int t  = threadIdx.x;
    const int n0 = blockIdx.x * 32;   // grid.x = n-tiles (XCD locality)
    const int m0 = blockIdx.y * 64;   // grid.y = m-tiles

    // X staging: row sr (0..31), k-quad sk (0..15) -> one float4 per step
    const int sr = t >> 4;
    const int sk = t & 15;
    const float* ax = X + (n0 + sr) * ND + sk * 4;

    // P staging: m-column pm (0..63), k-octet pk (0..7) -> 8 strided f32 per step
    const int pm = t & 63;
    const int pk = t >> 6;
    const float* bp = P + (pk * 8) * NM + m0 + pm;

    const int lane = t & 63;
    const int wid  = t >> 6;          // 0..7
    const int wn   = wid >> 2;        // 0..1  (16n quadrant)
    const int wm   = wid & 3;         // 0..3  (16m quadrant)
    const int fr = lane & 15, fq = lane >> 4;

    float xacc = 0.f, pacc = 0.f;
    f32x4 acc = {0.f, 0.f, 0.f, 0.f};

    float4 a[2];
    float  b[2][8];

    // prologue loads (step 0)
    a[0] = *(const float4*)ax;
    #pragma unroll
    for (int j = 0; j < 8; ++j) b[0][j] = bp[j * NM];

    #pragma unroll
    for (int step = 0; step < 8; ++step) {
        const int cur = step & 1, nxt = cur ^ 1;

        // ---- early prefetch: issue next-step loads FIRST (staging VALU covers)
        if (step < 7) {
            const float* pax = ax + (step + 1) * 64;
            a[nxt] = *(const float4*)pax;
            const float* pbp = bp + (step + 1) * 64 * NM;
            #pragma unroll
            for (int j = 0; j < 8; ++j) b[nxt][j] = pbp[j * NM];
        }

        // ---- stage X: fold norm (f32), convert, b64 write
        {
            float4 av = a[cur];
            xacc = fmaf(av.x, av.x, xacc); xacc = fmaf(av.y, av.y, xacc);
            xacc = fmaf(av.z, av.z, xacc); xacc = fmaf(av.w, av.w, xacc);
            uint2 xw;
            xw.x = (unsigned)f2bf(av.x) | ((unsigned)f2bf(av.y) << 16);
            xw.y = (unsigned)f2bf(av.z) | ((unsigned)f2bf(av.w) << 16);
            *(uint2*)&As[cur][sr][sk * 4] = xw;
        }

        // ---- stage P: fold norm (f32), pack 8 k-consecutive bf16, b128 write
        {
            unsigned w[4];
            #pragma unroll
            for (int i = 0; i < 4; ++i) {
                float lo = b[cur][2 * i], hi = b[cur][2 * i + 1];
                pacc = fmaf(lo, lo, pacc); pacc = fmaf(hi, hi, pacc);
                w[i] = (unsigned)f2bf(lo) | ((unsigned)f2bf(hi) << 16);
            }
            *(uint4*)&Bs[cur][pm][pk * 8] = make_uint4(w[0], w[1], w[2], w[3]);
        }

        __syncthreads();   // LDS[cur] ready (1 barrier/step dbuf, race-free)

        #pragma unroll
        for (int s = 0; s < 2; ++s) {
            const int kk = s * 32 + fq * 8;
            short8 af = *(const short8*)&As[cur][wn * 16 + fr][kk];
            short8 bf = *(const short8*)&Bs[cur][wm * 16 + fr][kk];
            acc = __builtin_amdgcn_mfma_f32_16x16x32_bf16(af, bf, acc, 0, 0, 0);
        }
    }

    // ---- norm reductions
    #pragma unroll
    for (int off = 8; off > 0; off >>= 1) xacc += __shfl_down(xacc, off, 16);
    if (sk == 0) xx_s[sr] = xacc;
    pp_part[pk][pm] = pacc;
    __syncthreads();

    // ---- epilogue: C/D layout col=lane&15, row=(lane>>4)*4+reg  [m89/m91]
    const int col = wm * 16 + fr;
    float pv = 0.f;
    #pragma unroll
    for (int i = 0; i < 8; ++i) pv += pp_part[i][col];
    float* orow = out + (n0 + wn * 16) * NM + m0 + col;
    #pragma unroll
    for (int r = 0; r < 4; ++r) {
        const int rowl = fq * 4 + r;
        const float xv = xx_s[wn * 16 + rowl];
        orow[rowl * NM] = -0.5f * sqrtf(fmaxf(xv + pv - 2.f * acc[r], 0.f));
    }
}

extern "C" void kernel_launch(void* const* d_in, const int* in_sizes, int n_in,
                              void* d_out, int out_size, void* d_ws, size_t ws_size,
                              hipStream_t stream) {
    const float* x     = (const float*)d_in[0];   // (N, D) f32
    const float* proto = (const float*)d_in[1];   // (D, M) f32
    float* out = (float*)d_out;                   // (N, M) f32
    hipLaunchKernelGGL(fused_kernel, dim3(NN / 32, NM / 64), dim3(512), 0, stream,
                       x, proto, out);
}